// Round 9
// baseline (557.766 us; speedup 1.0000x reference)
//
#include <hip/hip_runtime.h>
#include <cstddef>

#define HH 64

// ---------------------------------------------------------------------------
// d_ws layout (computed device-side; C = num_classes lives only on device):
//   int scanb[C+N]   degrees -> per-block exclusive-scanned (partial)
//   int cur[C+N]     fill cursors (== segment degree after k_fill)
//   int part[1024]   exclusive-scanned block partials (scanb[i]+part[i>>8] =
//                    absolute segment start; no scan_add pass needed)
//   int melist[N+E]  class-member section [0,N), node-edge-col section [N,N+E)
//   float cmean[B*C*64]   class means
//   float g[B*C*64]       g = cmean @ W1  (projected class means)
// Linearity trick: h = (e+ctx)@W1+b1 = e@W1 + b1 + inv*sum_e g[col_e], so the
// MLP kernel only ever needs the h[64] accumulator live (no x[64] array ->
// no spill; VGPR ~85 instead of 128+).
// ---------------------------------------------------------------------------
struct WS {
  int* scanb;
  int* cur;
  int* part;
  int* melist;
  float* cmean;
  float* g;
};

__device__ __forceinline__ WS ws_layout(void* d_ws, int C, int N, int E, int B) {
  int* wi = (int*)d_ws;
  WS w;
  w.scanb  = wi;
  w.cur    = wi + (size_t)(C + N);
  w.part   = w.cur + (size_t)(C + N);
  w.melist = w.part + 1024;
  size_t fo = (size_t)2 * (C + N) + 1024 + (size_t)(N + E);
  fo = (fo + 3) & ~(size_t)3;
  w.cmean = (float*)d_ws + fo;
  w.g     = w.cmean + (size_t)B * C * HH;
  return w;
}

// K1: zero scanb + cur.
__global__ __launch_bounds__(256) void k_init(void* ws, const int* __restrict__ pC,
                                              int N, int E, int B) {
  int C = *pC;
  WS w = ws_layout(ws, C, N, E, B);
  size_t total = (size_t)2 * (C + N);
  size_t stride = (size_t)gridDim.x * blockDim.x;
  for (size_t i = (size_t)blockIdx.x * blockDim.x + threadIdx.x; i < total; i += stride)
    w.scanb[i] = 0;
}

// K2: degree count. idx<N: class degree of c2n_row[n]; else node degree of n2c_row[e].
__global__ __launch_bounds__(256) void k_count(const int* __restrict__ c2n_row,
                                               const int* __restrict__ n2c_row,
                                               void* ws, const int* __restrict__ pC,
                                               int N, int E, int B) {
  int C = *pC;
  WS w = ws_layout(ws, C, N, E, B);
  int idx = blockIdx.x * 256 + threadIdx.x;
  if (idx < N) {
    atomicAdd(&w.scanb[c2n_row[idx]], 1);
  } else if (idx < N + E) {
    atomicAdd(&w.scanb[C + n2c_row[idx - N]], 1);
  }
}

// K3a: per-256-block exclusive scan, block totals -> part[]. Grid MUST be 1024
// blocks so part[0..1023] is fully written (OOB blocks write 0).
__global__ __launch_bounds__(256) void k_scan_blk(void* ws, const int* __restrict__ pC,
                                                  int N, int E, int B) {
  int C = *pC;
  WS w = ws_layout(ws, C, N, E, B);
  int L = C + N;
  __shared__ int tmp[256];
  int gid = blockIdx.x * 256 + threadIdx.x;
  int v = (gid < L) ? w.scanb[gid] : 0;
  tmp[threadIdx.x] = v;
  __syncthreads();
#pragma unroll
  for (int off = 1; off < 256; off <<= 1) {
    int t = (threadIdx.x >= (unsigned)off) ? tmp[threadIdx.x - off] : 0;
    __syncthreads();
    tmp[threadIdx.x] += t;
    __syncthreads();
  }
  if (gid < L) w.scanb[gid] = tmp[threadIdx.x] - v;  // exclusive (within block)
  if (threadIdx.x == 255) w.part[blockIdx.x] = tmp[255];
}

// K3b: single-block exclusive scan of the 1024 partials. Consumers compute
// absolute offsets as scanb[i] + part[i>>8] (no separate add-back pass).
__global__ __launch_bounds__(1024) void k_scan_part(void* ws, const int* __restrict__ pC,
                                                    int N, int E, int B) {
  int C = *pC;
  WS w = ws_layout(ws, C, N, E, B);
  __shared__ int tmp[1024];
  int v = w.part[threadIdx.x];
  tmp[threadIdx.x] = v;
  __syncthreads();
#pragma unroll
  for (int off = 1; off < 1024; off <<= 1) {
    int t = (threadIdx.x >= (unsigned)off) ? tmp[threadIdx.x - off] : 0;
    __syncthreads();
    tmp[threadIdx.x] += t;
    __syncthreads();
  }
  w.part[threadIdx.x] = tmp[threadIdx.x] - v;
}

// K4: cursor fill. melist gets absolute positions (edge section lands in [N,N+E)).
__global__ __launch_bounds__(256) void k_fill(const int* __restrict__ c2n_row,
                                              const int* __restrict__ n2c_row,
                                              const int* __restrict__ n2c_col,
                                              void* ws, const int* __restrict__ pC,
                                              int N, int E, int B) {
  int C = *pC;
  WS w = ws_layout(ws, C, N, E, B);
  int idx = blockIdx.x * 256 + threadIdx.x;
  if (idx < N) {
    int c = c2n_row[idx];
    int pos = w.scanb[c] + w.part[c >> 8] + atomicAdd(&w.cur[c], 1);
    w.melist[pos] = idx;
  } else if (idx < N + E) {
    int e = idx - N;
    int seg = C + n2c_row[e];
    int pos = w.scanb[seg] + w.part[seg >> 8] + atomicAdd(&w.cur[seg], 1);
    w.melist[pos] = n2c_col[e];
  }
}

// K5: class means, wave per class (lane = feature), loops all B batches to
// reuse the member list. Coalesced 256B reads/writes, no atomics.
// Empty classes write 0 (matches reference: sum 0 / max(cnt,1)).
__global__ __launch_bounds__(256) void k_class_mean(const float* __restrict__ emb,
                                                    void* ws, const int* __restrict__ pC,
                                                    int N, int E, int B) {
  int C = *pC;
  WS w = ws_layout(ws, C, N, E, B);
  int lane = threadIdx.x & 63;
  int wav = (int)((blockIdx.x * (size_t)blockDim.x + threadIdx.x) >> 6);
  int nw = (int)(((size_t)gridDim.x * blockDim.x) >> 6);
  size_t NH = (size_t)N * HH;
  size_t CH = (size_t)C * HH;
  for (int c = wav; c < C; c += nw) {
    int start = w.scanb[c] + w.part[c >> 8];
    int deg = w.cur[c];
    float inv = 1.0f / fmaxf((float)deg, 1.0f);
    if (B == 4) {
      float s0 = 0, s1 = 0, s2 = 0, s3 = 0;
      for (int k = 0; k < deg; ++k) {
        int m = w.melist[start + k];  // wave-uniform -> broadcast
        size_t base = (size_t)m * HH + lane;
        s0 += emb[base];
        s1 += emb[base + NH];
        s2 += emb[base + 2 * NH];
        s3 += emb[base + 3 * NH];
      }
      size_t o = (size_t)c * HH + lane;
      w.cmean[o] = s0 * inv;
      w.cmean[o + CH] = s1 * inv;
      w.cmean[o + 2 * CH] = s2 * inv;
      w.cmean[o + 3 * CH] = s3 * inv;
    } else {
      for (int b = 0; b < B; ++b) {
        float s = 0;
        for (int k = 0; k < deg; ++k) {
          int m = w.melist[start + k];
          s += emb[((size_t)b * N + m) * HH + lane];
        }
        w.cmean[((size_t)b * C + c) * HH + lane] = s * inv;
      }
    }
  }
}

// K6: g = cmean @ W1 (no bias). Thread per (b,c) row, streaming: only the
// 64-float accumulator is live (cmean row consumed float4-at-a-time).
__global__ __launch_bounds__(256) void k_g(const float* __restrict__ W1, void* ws,
                                           const int* __restrict__ pC,
                                           int N, int E, int B) {
  __shared__ float w1s[HH * HH];
  for (int t = threadIdx.x; t < HH * HH / 4; t += 256)
    ((float4*)w1s)[t] = ((const float4*)W1)[t];
  __syncthreads();

  int C = *pC;
  WS w = ws_layout(ws, C, N, E, B);
  size_t total = (size_t)B * C;
  size_t stride = (size_t)gridDim.x * 256;
  for (size_t r = (size_t)blockIdx.x * 256 + threadIdx.x; r < total; r += stride) {
    const float4* src = (const float4*)(w.cmean + r * HH);
    float h[HH];
#pragma unroll
    for (int k = 0; k < HH; ++k) h[k] = 0.0f;
#pragma unroll
    for (int q = 0; q < HH / 4; ++q) {
      float4 cv = src[q];
#pragma unroll
      for (int j = 0; j < 4; ++j) {
        float ci = (j == 0) ? cv.x : (j == 1) ? cv.y : (j == 2) ? cv.z : cv.w;
        const float4* wrow = (const float4*)(w1s + (4 * q + j) * HH);  // uniform
#pragma unroll
        for (int kq = 0; kq < HH / 4; ++kq) {
          float4 wv = wrow[kq];
          h[4 * kq + 0] += ci * wv.x;
          h[4 * kq + 1] += ci * wv.y;
          h[4 * kq + 2] += ci * wv.z;
          h[4 * kq + 3] += ci * wv.w;
        }
      }
    }
    float4* dst = (float4*)(w.g + r * HH);
#pragma unroll
    for (int kq = 0; kq < HH / 4; ++kq)
      dst[kq] = make_float4(h[4 * kq], h[4 * kq + 1], h[4 * kq + 2], h[4 * kq + 3]);
  }
}

// K7: per-row fused: h = b1 + e@W1 + inv*sum_e g[col_e]; LayerNorm; ReLU;
// logit = h@W2 + b2. Only h[64] live throughout (emb streamed, g added
// elementwise) -> low VGPR, deep ILP on the gather adds.
__global__ __launch_bounds__(256) void k_mlp(
    const float* __restrict__ emb, const float* __restrict__ W1,
    const float* __restrict__ b1, const float* __restrict__ gamma,
    const float* __restrict__ beta, const float* __restrict__ W2,
    const float* __restrict__ b2, void* ws, const int* __restrict__ pC,
    float* __restrict__ out, int N, int E, int B) {
  __shared__ float w1s[HH * HH];
  for (int t = threadIdx.x; t < HH * HH / 4; t += 256)
    ((float4*)w1s)[t] = ((const float4*)W1)[t];
  __syncthreads();

  int C = *pC;
  WS w = ws_layout(ws, C, N, E, B);

  int b = blockIdx.y;
  int n = blockIdx.x * 256 + threadIdx.x;
  if (n >= N) return;

  float h[HH];
#pragma unroll
  for (int q = 0; q < HH / 4; ++q) {
    float4 bv = *(const float4*)(b1 + 4 * q);
    h[4 * q + 0] = bv.x;
    h[4 * q + 1] = bv.y;
    h[4 * q + 2] = bv.z;
    h[4 * q + 3] = bv.w;
  }

  // h += e @ W1, streaming the emb row (no x array).
  const float4* e4 = (const float4*)(emb + ((size_t)b * N + n) * HH);
#pragma unroll
  for (int q = 0; q < HH / 4; ++q) {
    float4 ev = e4[q];
#pragma unroll
    for (int j = 0; j < 4; ++j) {
      float xi = (j == 0) ? ev.x : (j == 1) ? ev.y : (j == 2) ? ev.z : ev.w;
      const float4* wrow = (const float4*)(w1s + (4 * q + j) * HH);  // uniform
#pragma unroll
      for (int kq = 0; kq < HH / 4; ++kq) {
        float4 wv = wrow[kq];
        h[4 * kq + 0] += xi * wv.x;
        h[4 * kq + 1] += xi * wv.y;
        h[4 * kq + 2] += xi * wv.z;
        h[4 * kq + 3] += xi * wv.w;
      }
    }
  }

  // h += inv * sum_e g[col_e]  (elementwise adds, independent loads).
  int seg = C + n;
  int start = w.scanb[seg] + w.part[seg >> 8];
  int deg = w.cur[seg];
  if (deg > 0) {
    float inv = 1.0f / (float)deg;
    for (int k = 0; k < deg; ++k) {
      int col = w.melist[start + k];
      const float4* g4 = (const float4*)(w.g + ((size_t)b * C + col) * HH);
#pragma unroll
      for (int q = 0; q < HH / 4; ++q) {
        float4 gv = g4[q];
        h[4 * q + 0] += inv * gv.x;
        h[4 * q + 1] += inv * gv.y;
        h[4 * q + 2] += inv * gv.z;
        h[4 * q + 3] += inv * gv.w;
      }
    }
  }

  float mu = 0.0f;
#pragma unroll
  for (int j = 0; j < HH; ++j) mu += h[j];
  mu *= (1.0f / HH);
  float var = 0.0f;
#pragma unroll
  for (int j = 0; j < HH; ++j) {
    float d = h[j] - mu;
    var += d * d;
  }
  var *= (1.0f / HH);
  float rs = rsqrtf(var + 1e-5f);

  float logit = b2[0];
#pragma unroll
  for (int j = 0; j < HH; ++j) {
    float hn = (h[j] - mu) * rs * gamma[j] + beta[j];
    hn = fmaxf(hn, 0.0f);
    logit += hn * W2[j];
  }
  out[(size_t)b * N + n] = logit;
}

extern "C" void kernel_launch(void* const* d_in, const int* in_sizes, int n_in,
                              void* d_out, int out_size, void* d_ws,
                              size_t ws_size, hipStream_t stream) {
  const float* emb   = (const float*)d_in[0];
  const float* W1    = (const float*)d_in[1];
  const float* b1    = (const float*)d_in[2];
  const float* gamma = (const float*)d_in[3];
  const float* beta  = (const float*)d_in[4];
  const float* W2    = (const float*)d_in[5];
  const float* b2    = (const float*)d_in[6];
  const int* n2c_row = (const int*)d_in[7];
  const int* n2c_col = (const int*)d_in[8];
  const int* c2n_row = (const int*)d_in[9];
  // c2n_col is arange(N) in this problem; the CSR build only needs c2n_row.
  const int* pC      = (const int*)d_in[11];

  int E = in_sizes[7];
  int N = in_sizes[9];
  int H = in_sizes[2];  // 64; kernels assume HH==64
  int B = in_sizes[0] / (N * H);
  (void)n_in; (void)ws_size; (void)out_size;

  float* out = (float*)d_out;

  int ne_blocks = (N + E + 255) / 256;

  k_init<<<1024, 256, 0, stream>>>(d_ws, pC, N, E, B);
  k_count<<<ne_blocks, 256, 0, stream>>>(c2n_row, n2c_row, d_ws, pC, N, E, B);
  k_scan_blk<<<1024, 256, 0, stream>>>(d_ws, pC, N, E, B);  // grid MUST be 1024
  k_scan_part<<<1, 1024, 0, stream>>>(d_ws, pC, N, E, B);
  k_fill<<<ne_blocks, 256, 0, stream>>>(c2n_row, n2c_row, n2c_col, d_ws, pC, N, E, B);

  k_class_mean<<<4096, 256, 0, stream>>>(emb, d_ws, pC, N, E, B);
  k_g<<<2048, 256, 0, stream>>>(W1, d_ws, pC, N, E, B);

  dim3 gm((unsigned)((N + 255) / 256), (unsigned)B);
  k_mlp<<<gm, 256, 0, stream>>>(emb, W1, b1, gamma, beta, W2, b2, d_ws, pC, out,
                                N, E, B);
}